// Round 2
// baseline (638.574 us; speedup 1.0000x reference)
//
#include <hip/hip_runtime.h>
#include <hip/hip_bf16.h>

#define LEAK 0.01f
#define BN_EPS 1e-5f

using frag_b16 = __attribute__((ext_vector_type(8))) short;
using f32x4    = __attribute__((ext_vector_type(4))) float;

__device__ __forceinline__ unsigned short f2bf(float f) {
    union { float f; unsigned int i; } v;
    v.f = f;
    unsigned int u = v.i;
    unsigned int r = (u + 0x7fffu + ((u >> 16) & 1u)) >> 16;  // RNE
    return (unsigned short)r;
}

__device__ __forceinline__ unsigned int pk_bf16(float lo, float hi) {
    __hip_bfloat162 h = __float22bfloat162_rn(make_float2(lo, hi));
    union { __hip_bfloat162 h; unsigned int u; } c;
    c.h = h;
    return c.u;  // lo in low 16 bits
}

// Repack W [9][CIN][128] fp32 -> Wt [9][128][CIN] bf16.
__global__ void transpose_w(const float* __restrict__ w,
                            unsigned short* __restrict__ wt,
                            int cin, int total) {
    int i = blockIdx.x * 256 + threadIdx.x;
    if (i >= total) return;
    int co   = i & 127;
    int rest = i >> 7;        // k*cin + ci
    int ci   = rest % cin;
    int k    = rest / cin;
    wt[((size_t)k * 128 + co) * cin + ci] = f2bf(w[i]);
}

// out[n, co] = actbn( sum_k sum_ci f[nbr[k,n], ci] * W[k,ci,co] )  (+ addsrc)
// Block: 128 rows x 128 cout, 256 threads (4 waves, 2x2), 16x16x32 bf16 MFMA.
template <int CIN, bool IN_F32, bool OUT_F32, bool ADD>
__global__ __launch_bounds__(256) void conv_mfma(
    const void*  __restrict__ fin_,   // [N][CIN] fp32 or bf16
    const int*   __restrict__ nbr,    // [9][N]
    const unsigned short* __restrict__ wt,   // [9][128][CIN] bf16 pre-transposed
    const float* __restrict__ bn,     // [4][128] fp32
    const float* __restrict__ addsrc, // [N][128] fp32 or null
    void*        __restrict__ out_,   // [N][128] fp32 or bf16
    int N) {
    constexpr int SEGS   = CIN / 8;      // 16B bf16 segments per row
    constexpr int RPP    = 256 / SEGS;   // rows staged per pass
    constexpr int PASSES = 128 / RPP;

    __shared__ unsigned short ldsA[128 * CIN];  // gathered A tile (swizzled)
    __shared__ unsigned short ldsW[128 * CIN];  // Wt[k] tile (swizzled)

    const int tid   = threadIdx.x;
    const int lane  = tid & 63;
    const int wave  = tid >> 6;
    const int waveM = wave >> 1;
    const int waveN = wave & 1;
    const int l16   = lane & 15;
    const int quad  = lane >> 4;
    const int n0    = blockIdx.x * 128;

    const int srow = tid / SEGS;
    const int sseg = tid % SEGS;

    f32x4 acc[4][4] = {};

    for (int k = 0; k < 9; ++k) {
        if (k) __syncthreads();
        // ---- stage gathered A rows (idx < 0 or n >= N -> zeros) ----
        #pragma unroll
        for (int p = 0; p < PASSES; ++p) {
            int r = p * RPP + srow;
            int n = n0 + r;
            int idx = (n < N) ? nbr[(size_t)k * N + n] : -1;
            uint4 v = make_uint4(0u, 0u, 0u, 0u);
            if (IN_F32) {
                const float* fin = (const float*)fin_;
                float4 a = make_float4(0.f, 0.f, 0.f, 0.f);
                float4 b = make_float4(0.f, 0.f, 0.f, 0.f);
                if (idx >= 0) {
                    const float4* p4 = (const float4*)(fin + (size_t)idx * CIN) + sseg * 2;
                    a = p4[0];
                    b = p4[1];
                }
                v.x = pk_bf16(a.x, a.y);
                v.y = pk_bf16(a.z, a.w);
                v.z = pk_bf16(b.x, b.y);
                v.w = pk_bf16(b.z, b.w);
            } else {
                const unsigned short* fin = (const unsigned short*)fin_;
                if (idx >= 0) v = *((const uint4*)(fin + (size_t)idx * CIN) + sseg);
            }
            *(uint4*)(ldsA + r * CIN + ((sseg ^ (r & 7)) << 3)) = v;
        }
        // ---- stage Wt[k] tile ----
        const unsigned short* wk = wt + (size_t)k * 128 * CIN;
        #pragma unroll
        for (int p = 0; p < PASSES; ++p) {
            int r = p * RPP + srow;
            *(uint4*)(ldsW + r * CIN + ((sseg ^ (r & 7)) << 3)) =
                *((const uint4*)(wk + r * CIN) + sseg);
        }
        __syncthreads();

        // ---- MFMA over K chunks of 32 ----
        #pragma unroll
        for (int c = 0; c < CIN / 32; ++c) {
            frag_b16 af[4], bf[4];
            #pragma unroll
            for (int i = 0; i < 4; ++i) {
                int seg  = (c * 4 + quad) ^ (l16 & 7);
                int rowA = waveM * 64 + i * 16 + l16;
                af[i] = *(const frag_b16*)(ldsA + rowA * CIN + (seg << 3));
                int rowB = waveN * 64 + i * 16 + l16;
                bf[i] = *(const frag_b16*)(ldsW + rowB * CIN + (seg << 3));
            }
            #pragma unroll
            for (int mi = 0; mi < 4; ++mi)
                #pragma unroll
                for (int ni = 0; ni < 4; ++ni)
                    acc[mi][ni] = __builtin_amdgcn_mfma_f32_16x16x32_bf16(
                        af[mi], bf[ni], acc[mi][ni], 0, 0, 0);
        }
    }

    // ---- epilogue: LeakyReLU -> BN (-> +shortcut) -> store ----
    float sc[4], sh[4];
    int   col[4];
    #pragma unroll
    for (int ni = 0; ni < 4; ++ni) {
        int c = waveN * 64 + ni * 16 + l16;
        col[ni] = c;
        float g = bn[c];
        float b = bn[128 + c];
        float m = bn[256 + c];
        float v = bn[384 + c];
        float s = g * rsqrtf(v + BN_EPS);
        sc[ni] = s;
        sh[ni] = b - m * s;
    }
    #pragma unroll
    for (int mi = 0; mi < 4; ++mi) {
        int rbase = n0 + waveM * 64 + mi * 16 + quad * 4;
        #pragma unroll
        for (int r = 0; r < 4; ++r) {
            int n = rbase + r;
            if (n < N) {
                #pragma unroll
                for (int ni = 0; ni < 4; ++ni) {
                    float x = acc[mi][ni][r];
                    x = (x >= 0.0f) ? x : LEAK * x;
                    x = x * sc[ni] + sh[ni];
                    if (ADD) x += addsrc[(size_t)n * 128 + col[ni]];
                    if (OUT_F32) {
                        ((float*)out_)[(size_t)n * 128 + col[ni]] = x;
                    } else {
                        ((unsigned short*)out_)[(size_t)n * 128 + col[ni]] = f2bf(x);
                    }
                }
            }
        }
    }
}

extern "C" void kernel_launch(void* const* d_in, const int* in_sizes, int n_in,
                              void* d_out, int out_size, void* d_ws, size_t ws_size,
                              hipStream_t stream) {
    const float* feats = (const float*)d_in[0];
    const float* W00   = (const float*)d_in[1];
    const float* W01   = (const float*)d_in[2];
    const float* W10   = (const float*)d_in[3];
    const float* W11   = (const float*)d_in[4];
    const float* bn00  = (const float*)d_in[5];
    const float* bn01  = (const float*)d_in[6];
    const float* bn10  = (const float*)d_in[7];
    const float* bn11  = (const float*)d_in[8];
    const int* nbr133  = (const int*)d_in[9];
    const int* nbr313  = (const int*)d_in[10];
    const int N = in_sizes[0] / 64;

    // ws layout: bufA = bf16 [N][128] intermediate (s1, then r1); then bf16 weights.
    // s2 lives in d_out as fp32 (conv2 writes it; conv4 reads each element in the
    // same thread that overwrites it -> no hazard).
    char* ws = (char*)d_ws;
    unsigned short* bufA = (unsigned short*)ws;
    unsigned short* wt00 = (unsigned short*)(ws + (size_t)N * 128 * 2);
    unsigned short* wt01 = wt00 + 9 * 128 * 64;
    unsigned short* wt10 = wt01 + 9 * 128 * 128;
    unsigned short* wt11 = wt10 + 9 * 128 * 64;
    float* outF = (float*)d_out;

    const int t64  = 9 * 64 * 128;
    const int t128 = 9 * 128 * 128;
    hipLaunchKernelGGL(transpose_w, dim3((t64  + 255) / 256), dim3(256), 0, stream, W00, wt00, 64,  t64);
    hipLaunchKernelGGL(transpose_w, dim3((t128 + 255) / 256), dim3(256), 0, stream, W01, wt01, 128, t128);
    hipLaunchKernelGGL(transpose_w, dim3((t64  + 255) / 256), dim3(256), 0, stream, W10, wt10, 64,  t64);
    hipLaunchKernelGGL(transpose_w, dim3((t128 + 255) / 256), dim3(256), 0, stream, W11, wt11, 128, t128);

    const int blocks = (N + 127) / 128;
    // s1 = actbn(conv133(feats)) -> bufA (bf16)
    hipLaunchKernelGGL((conv_mfma<64, true, false, false>), dim3(blocks), dim3(256), 0, stream,
                       (const void*)feats, nbr133, wt00, bn00, (const float*)nullptr, (void*)bufA, N);
    // s2 = actbn(conv313(s1)) -> d_out (fp32)
    hipLaunchKernelGGL((conv_mfma<128, false, true, false>), dim3(blocks), dim3(256), 0, stream,
                       (const void*)bufA, nbr313, wt01, bn01, (const float*)nullptr, (void*)outF, N);
    // r1 = actbn(conv313(feats)) -> bufA (bf16)
    hipLaunchKernelGGL((conv_mfma<64, true, false, false>), dim3(blocks), dim3(256), 0, stream,
                       (const void*)feats, nbr313, wt10, bn10, (const float*)nullptr, (void*)bufA, N);
    // out = actbn(conv133(r1)) + s2 -> d_out (fp32)
    hipLaunchKernelGGL((conv_mfma<128, false, true, true>), dim3(blocks), dim3(256), 0, stream,
                       (const void*)bufA, nbr133, wt11, bn11, outF, (void*)outF, N);
}